// Round 1
// 352.268 us; speedup vs baseline: 1.0904x; 1.0904x over previous
//
#include <hip/hip_runtime.h>

#define NH 4
#define HD 128
#define BS 32
#define STRIDE 16

typedef float  floatx4 __attribute__((ext_vector_type(4)));
typedef __bf16 bf16x8  __attribute__((ext_vector_type(8)));
typedef __bf16 bf16x2  __attribute__((ext_vector_type(2)));
typedef unsigned short u16x8 __attribute__((ext_vector_type(8)));

__device__ __forceinline__ unsigned short f2bf(float f) {
  unsigned u = __builtin_bit_cast(unsigned, f);
  u += 0x7FFFu + ((u >> 16) & 1u);   // RTNE (inputs finite)
  return (unsigned short)(u >> 16);
}

__device__ __forceinline__ bf16x8 cvt8(float4 lo, float4 hi) {
  bf16x8 r;
#if __has_builtin(__builtin_amdgcn_cvt_pk_bf16_f32)
  bf16x2 p0 = __builtin_bit_cast(bf16x2, __builtin_amdgcn_cvt_pk_bf16_f32(lo.x, lo.y));
  bf16x2 p1 = __builtin_bit_cast(bf16x2, __builtin_amdgcn_cvt_pk_bf16_f32(lo.z, lo.w));
  bf16x2 p2 = __builtin_bit_cast(bf16x2, __builtin_amdgcn_cvt_pk_bf16_f32(hi.x, hi.y));
  bf16x2 p3 = __builtin_bit_cast(bf16x2, __builtin_amdgcn_cvt_pk_bf16_f32(hi.z, hi.w));
  r[0] = p0[0]; r[1] = p0[1]; r[2] = p1[0]; r[3] = p1[1];
  r[4] = p2[0]; r[5] = p2[1]; r[6] = p3[0]; r[7] = p3[1];
#else
  u16x8 t;
  t[0] = f2bf(lo.x); t[1] = f2bf(lo.y); t[2] = f2bf(lo.z); t[3] = f2bf(lo.w);
  t[4] = f2bf(hi.x); t[5] = f2bf(hi.y); t[6] = f2bf(hi.z); t[7] = f2bf(hi.w);
  r = __builtin_bit_cast(bf16x8, t);
#endif
  return r;
}

__device__ __forceinline__ void gld16(const unsigned short* g, unsigned short* l) {
  __builtin_amdgcn_global_load_lds(
      (const __attribute__((address_space(1))) unsigned int*)(g),
      (__attribute__((address_space(3))) unsigned int*)(l), 16, 0, 0);
}

// Prep: LDS-tiled transpose of w into wt layout [mat][j][k0][fq][e][dq] (bf16),
// so B staging is contiguous per chunk and ds_read_b128 frags are
// 2-way-bank aliased (free). Block 256 (last) writes the cu_out prefix tail.
__global__ void prep_kernel(const float* __restrict__ wk, const float* __restrict__ wv,
                            unsigned short* __restrict__ wt,
                            const int* __restrict__ cu, int num_seqs,
                            float* __restrict__ tail) {
  const int bx = blockIdx.x;
  if (bx == 2 * BS * 4) {
    if (threadIdx.x == 0) {
      int acc = 0;
      tail[0] = 0.0f;
      for (int b = 0; b < num_seqs; ++b) {
        int n = cu[b + 1] - cu[b];
        acc += (n - BS) / STRIDE;
        tail[b + 1] = (float)acc;
      }
    }
    return;
  }
  const int mat = bx >> 7;
  const int j   = (bx >> 2) & 31;
  const int k0  = bx & 3;
  const float* __restrict__ w =
      (mat ? wv : wk) + (size_t)j * (HD * HD) + (size_t)k0 * 32 * HD;
  __shared__ unsigned short tile[32][HD];
  const int t = threadIdx.x;
  const int r = t >> 3, c = (t & 7) * 16;
#pragma unroll
  for (int i = 0; i < 16; i += 4) {
    float4 f = *(const float4*)(w + r * HD + c + i);
    tile[r][c + i + 0] = f2bf(f.x);
    tile[r][c + i + 1] = f2bf(f.y);
    tile[r][c + i + 2] = f2bf(f.z);
    tile[r][c + i + 3] = f2bf(f.w);
  }
  __syncthreads();
  unsigned short* dst =
      wt + (size_t)mat * (BS * HD * HD) + (size_t)j * 16384 + k0 * 4096;
#pragma unroll
  for (int it = 0; it < 2; ++it) {
    int fi = t + it * 256;      // 0..511 over (fq, e)
    int fq = fi >> 7, e = fi & 127;
    u16x8 fr;
#pragma unroll
    for (int dq = 0; dq < 8; ++dq) fr[dq] = tile[fq * 8 + dq][e];
    *(u16x8*)(dst + fq * 1024 + e * 8) = fr;
  }
}

// Main GEMM, v2: M-tile 128 (4 waves x 32m), full N=128, grid = 1 block/CU.
// B double-buffered in LDS (2 x 32KB) via global_load_lds; A double-buffered in
// registers. Counted s_waitcnt vmcnt(24) per step (never a full drain in the
// loop) so ~24 VMEM ops/wave stay in flight across both raw barriers.
// K-order (j ascending, k0 ascending) identical to v1 -> bit-identical output.
__global__ __launch_bounds__(256, 1) void kvc_gemm(
    const float* __restrict__ kp, const float* __restrict__ vp,
    const unsigned short* __restrict__ wt, const int* __restrict__ cu,
    float* __restrict__ out, long out_half, int M_total, int num_seqs) {

  __shared__ __align__(16) unsigned short Bs[2][16384];   // 2 x 32 KB stages

  const int mat = blockIdx.y;
  const float* __restrict__ x = mat ? vp : kp;
  const unsigned short* __restrict__ wmat = wt + (size_t)mat * (BS * HD * HD);
  float* __restrict__ outp = out + (size_t)mat * out_half;

  const int tid = threadIdx.x, wid = tid >> 6, lane = tid & 63;
  const int fl = lane & 15, fq = lane >> 4;
  const int mbase = blockIdx.x * 128 + wid * 32;

  // Per-lane token bases for the two 16-row m-fragments.
  const float* arow[2];
#pragma unroll
  for (int mf = 0; mf < 2; ++mf) {
    int m = mbase + mf * 16 + fl;
    int mc = m < M_total ? m : M_total - 1;
    int o = mc >> 2, h = mc & 3;
    int tb = 0, accb = 0;
    for (int b = 0; b < num_seqs; ++b) {
      int c0 = cu[b], c1 = cu[b + 1];
      int ol = (c1 - c0 - BS) / STRIDE;
      if (o >= accb && o - accb < ol) tb = c0 + (o - accb) * STRIDE;
      accb += ol;
    }
    arow[mf] = x + ((size_t)tb * NH + h) * HD + fq * 8;
  }

  floatx4 acc[2][8];
#pragma unroll
  for (int mf = 0; mf < 2; ++mf)
#pragma unroll
    for (int ni = 0; ni < 8; ++ni) acc[mf][ni] = (floatx4){0.f, 0.f, 0.f, 0.f};

  float4 a[2][2][4][2];   // [parity][mf][k0][half]

  // Stage full j-slice (32 KB) into buf P: 8 gld16/lane, linear dest.
#define BSTAGE(J, P)                                                        \
  {                                                                         \
    const unsigned short* s_ = wmat + (size_t)(J) * 16384 + tid * 8;        \
    _Pragma("unroll") for (int i_ = 0; i_ < 8; ++i_)                        \
        gld16(s_ + i_ * 2048, &Bs[(P)][i_ * 2048 + tid * 8]);               \
  }

  // Prefetch A for column j into parity P: 16 dwordx4/lane.
#define ALOAD(JN, P)                                                        \
  {                                                                         \
    _Pragma("unroll") for (int mf_ = 0; mf_ < 2; ++mf_) {                   \
      const float* ar_ = arow[mf_] + (size_t)(JN) * (NH * HD);              \
      _Pragma("unroll") for (int k_ = 0; k_ < 4; ++k_) {                    \
        a[(P)][mf_][k_][0] = *(const float4*)(ar_ + k_ * 32);               \
        a[(P)][mf_][k_][1] = *(const float4*)(ar_ + k_ * 32 + 4);           \
      }                                                                     \
    }                                                                       \
  }

  // 64 MFMA: 2 m-frags x 8 n-frags x 4 k0, B-frag reused across m.
#define COMPUTE(P)                                                          \
  {                                                                         \
    bf16x8 af_[2][4];                                                       \
    _Pragma("unroll") for (int mf_ = 0; mf_ < 2; ++mf_)                     \
        _Pragma("unroll") for (int k_ = 0; k_ < 4; ++k_)                    \
            af_[mf_][k_] = cvt8(a[(P)][mf_][k_][0], a[(P)][mf_][k_][1]);    \
    _Pragma("unroll") for (int k_ = 0; k_ < 4; ++k_) {                      \
      _Pragma("unroll") for (int ni_ = 0; ni_ < 8; ++ni_) {                 \
        bf16x8 bf_ = *(const bf16x8*)&Bs[(P)][k_ * 4096 + fq * 1024 +       \
                                           (ni_ * 16 + fl) * 8];            \
        acc[0][ni_] = __builtin_amdgcn_mfma_f32_16x16x32_bf16(              \
            af_[0][k_], bf_, acc[0][ni_], 0, 0, 0);                         \
        acc[1][ni_] = __builtin_amdgcn_mfma_f32_16x16x32_bf16(              \
            af_[1][k_], bf_, acc[1][ni_], 0, 0, 0);                         \
      }                                                                     \
    }                                                                       \
  }

#define VWAIT_(N) asm volatile("s_waitcnt vmcnt(" #N ")" ::: "memory")
#define VWAIT(N) VWAIT_(N)

  // One K-step. Barrier #1: all waves done reading buf[P^1] (prev step).
  // Issue next stage+prefetch, counted wait (prev step's 24 ops landed,
  // this step's 24 stay in flight), barrier #2: buf[P] visible to all.
#define STEP(J, P, JN, NV, PRE)                                             \
  {                                                                         \
    __builtin_amdgcn_s_barrier();                                           \
    __builtin_amdgcn_sched_barrier(0);                                      \
    if (PRE) {                                                              \
      BSTAGE((JN), (P) ^ 1);                                                \
      ALOAD((JN), (P) ^ 1);                                                 \
    }                                                                       \
    __builtin_amdgcn_sched_barrier(0);                                      \
    VWAIT(NV);                                                              \
    __builtin_amdgcn_sched_barrier(0);                                      \
    __builtin_amdgcn_s_barrier();                                           \
    __builtin_amdgcn_sched_barrier(0);                                      \
    COMPUTE(P);                                                             \
  }

  BSTAGE(0, 0);
  ALOAD(0, 0);
  for (int j = 0; j < 30; j += 2) {
    STEP(j, 0, j + 1, 24, 1);
    STEP(j + 1, 1, j + 2, 24, 1);
  }
  STEP(30, 0, 31, 24, 1);
  STEP(31, 1, 0, 0, 0);

#undef STEP
#undef VWAIT
#undef VWAIT_
#undef COMPUTE
#undef ALOAD
#undef BSTAGE

  // C/D: col = fl (= e offset), row = fq*4 + r per 16-row fragment.
#pragma unroll
  for (int ni = 0; ni < 8; ++ni) {
#pragma unroll
    for (int r = 0; r < 4; ++r) {
      const int mg0 = mbase + fq * 4 + r;
      const int mg1 = mbase + 16 + fq * 4 + r;
      if (mg0 < M_total) outp[(size_t)mg0 * HD + ni * 16 + fl] = acc[0][ni][r];
      if (mg1 < M_total) outp[(size_t)mg1 * HD + ni * 16 + fl] = acc[1][ni][r];
    }
  }
}

// Fallback path if ws is too small for the weight transpose.
__global__ void tail_kernel(const int* __restrict__ cu, int num_seqs,
                            float* __restrict__ tail) {
  if (threadIdx.x == 0) {
    int acc = 0;
    tail[0] = 0.0f;
    for (int b = 0; b < num_seqs; ++b) {
      int n = cu[b + 1] - cu[b];
      acc += (n - BS) / STRIDE;
      tail[b + 1] = (float)acc;
    }
  }
}

__global__ void kvc_naive(const float* __restrict__ kp, const float* __restrict__ vp,
                          const float* __restrict__ wk, const float* __restrict__ wv,
                          const int* __restrict__ cu, int num_seqs,
                          float* __restrict__ out, long out_half) {
  int o = blockIdx.x, h = blockIdx.y, mat = blockIdx.z;
  int e = threadIdx.x;
  int acc = 0, base = -1;
  for (int b = 0; b < num_seqs; ++b) {
    int n = cu[b + 1] - cu[b];
    int ol = (n - BS) / STRIDE;
    if (o < acc + ol) { base = cu[b] + (o - acc) * STRIDE; break; }
    acc += ol;
  }
  if (base < 0) return;
  const float* x = mat ? vp : kp;
  const float* w = mat ? wv : wk;
  float s = 0.f;
  for (int j = 0; j < BS; ++j)
    for (int d = 0; d < HD; ++d)
      s += x[(size_t)(base + j) * (NH * HD) + h * HD + d] * w[(j * HD + d) * HD + e];
  out[(size_t)mat * out_half + ((size_t)o * NH + h) * HD + e] = s;
}

extern "C" void kernel_launch(void* const* d_in, const int* in_sizes, int n_in,
                              void* d_out, int out_size, void* d_ws, size_t ws_size,
                              hipStream_t stream) {
  const float* kp = (const float*)d_in[0];
  const float* vp = (const float*)d_in[1];
  const float* wk = (const float*)d_in[2];
  const float* wv = (const float*)d_in[3];
  const int* cu = (const int*)d_in[4];
  const int num_seqs = in_sizes[4] - 1;
  float* out = (float*)d_out;

  const long total_out = ((long)out_size - (num_seqs + 1)) / (2L * NH * HD);
  const long out_half = total_out * NH * HD;
  const int M_total = (int)(total_out * NH);
  float* tail = out + 2 * out_half;

  const size_t need_ws = (size_t)2 * BS * HD * HD * sizeof(unsigned short);
  if (ws_size >= need_ws) {
    unsigned short* wt = (unsigned short*)d_ws;
    prep_kernel<<<2 * BS * 4 + 1, 256, 0, stream>>>(wk, wv, wt, cu, num_seqs, tail);
    dim3 grid((M_total + 127) / 128, 2);
    kvc_gemm<<<grid, 256, 0, stream>>>(kp, vp, wt, cu, out, out_half, M_total,
                                       num_seqs);
  } else {
    tail_kernel<<<1, 64, 0, stream>>>(cu, num_seqs, tail);
    dim3 grid((unsigned)total_out, NH, 2);
    kvc_naive<<<grid, HD, 0, stream>>>(kp, vp, wk, wv, cu, num_seqs, out, out_half);
  }
}

// Round 2
// 341.882 us; speedup vs baseline: 1.1235x; 1.0304x over previous
//
#include <hip/hip_runtime.h>

#define NH 4
#define HD 128
#define BS 32
#define STRIDE 16

typedef float  floatx4 __attribute__((ext_vector_type(4)));
typedef __bf16 bf16x8  __attribute__((ext_vector_type(8)));
typedef __bf16 bf16x2  __attribute__((ext_vector_type(2)));
typedef unsigned short u16x8 __attribute__((ext_vector_type(8)));

__device__ __forceinline__ unsigned short f2bf(float f) {
  unsigned u = __builtin_bit_cast(unsigned, f);
  u += 0x7FFFu + ((u >> 16) & 1u);   // RTNE (inputs finite)
  return (unsigned short)(u >> 16);
}

__device__ __forceinline__ bf16x8 cvt8(float4 lo, float4 hi) {
  bf16x8 r;
#if __has_builtin(__builtin_amdgcn_cvt_pk_bf16_f32)
  bf16x2 p0 = __builtin_bit_cast(bf16x2, __builtin_amdgcn_cvt_pk_bf16_f32(lo.x, lo.y));
  bf16x2 p1 = __builtin_bit_cast(bf16x2, __builtin_amdgcn_cvt_pk_bf16_f32(lo.z, lo.w));
  bf16x2 p2 = __builtin_bit_cast(bf16x2, __builtin_amdgcn_cvt_pk_bf16_f32(hi.x, hi.y));
  bf16x2 p3 = __builtin_bit_cast(bf16x2, __builtin_amdgcn_cvt_pk_bf16_f32(hi.z, hi.w));
  r[0] = p0[0]; r[1] = p0[1]; r[2] = p1[0]; r[3] = p1[1];
  r[4] = p2[0]; r[5] = p2[1]; r[6] = p3[0]; r[7] = p3[1];
#else
  u16x8 t;
  t[0] = f2bf(lo.x); t[1] = f2bf(lo.y); t[2] = f2bf(lo.z); t[3] = f2bf(lo.w);
  t[4] = f2bf(hi.x); t[5] = f2bf(hi.y); t[6] = f2bf(hi.z); t[7] = f2bf(hi.w);
  r = __builtin_bit_cast(bf16x8, t);
#endif
  return r;
}

__device__ __forceinline__ void gld16(const unsigned short* g, unsigned short* l) {
  __builtin_amdgcn_global_load_lds(
      (const __attribute__((address_space(1))) unsigned int*)(g),
      (__attribute__((address_space(3))) unsigned int*)(l), 16, 0, 0);
}

// Prep: LDS-tiled transpose of w into wt layout [mat][j][k0][fq][e][dq] (bf16).
// Block 256 (last) writes the cu_out prefix tail.
__global__ void prep_kernel(const float* __restrict__ wk, const float* __restrict__ wv,
                            unsigned short* __restrict__ wt,
                            const int* __restrict__ cu, int num_seqs,
                            float* __restrict__ tail) {
  const int bx = blockIdx.x;
  if (bx == 2 * BS * 4) {
    if (threadIdx.x == 0) {
      int acc = 0;
      tail[0] = 0.0f;
      for (int b = 0; b < num_seqs; ++b) {
        int n = cu[b + 1] - cu[b];
        acc += (n - BS) / STRIDE;
        tail[b + 1] = (float)acc;
      }
    }
    return;
  }
  const int mat = bx >> 7;
  const int j   = (bx >> 2) & 31;
  const int k0  = bx & 3;
  const float* __restrict__ w =
      (mat ? wv : wk) + (size_t)j * (HD * HD) + (size_t)k0 * 32 * HD;
  __shared__ unsigned short tile[32][HD];
  const int t = threadIdx.x;
  const int r = t >> 3, c = (t & 7) * 16;
#pragma unroll
  for (int i = 0; i < 16; i += 4) {
    float4 f = *(const float4*)(w + r * HD + c + i);
    tile[r][c + i + 0] = f2bf(f.x);
    tile[r][c + i + 1] = f2bf(f.y);
    tile[r][c + i + 2] = f2bf(f.z);
    tile[r][c + i + 3] = f2bf(f.w);
  }
  __syncthreads();
  unsigned short* dst =
      wt + (size_t)mat * (BS * HD * HD) + (size_t)j * 16384 + k0 * 4096;
#pragma unroll
  for (int it = 0; it < 2; ++it) {
    int fi = t + it * 256;      // 0..511 over (fq, e)
    int fq = fi >> 7, e = fi & 127;
    u16x8 fr;
#pragma unroll
    for (int dq = 0; dq < 8; ++dq) fr[dq] = tile[fq * 8 + dq][e];
    *(u16x8*)(dst + fq * 1024 + e * 8) = fr;
  }
}

// Main GEMM, v3: M-tile 64 (4 waves x 16m), N 128 -> 510 blocks, 2 blocks/CU
// (phase-independent, breaks chip-wide lockstep). B double-buffered in TWO
// DISTINCT __shared__ arrays so alias analysis can't tie ds_reads of the
// read-buffer to the in-flight global_load_lds of the write-buffer (prevents
// a compiler-inserted vmcnt(0) full drain). Counted vmcnt(16) per step.
// K-order (j ascending, k0 ascending) identical -> bit-identical output.
__global__ __launch_bounds__(256, 2) void kvc_gemm(
    const float* __restrict__ kp, const float* __restrict__ vp,
    const unsigned short* __restrict__ wt, const int* __restrict__ cu,
    float* __restrict__ out, long out_half, int M_total, int num_seqs) {

  __shared__ __align__(16) unsigned short Bs0[16384];   // 32 KB stage A
  __shared__ __align__(16) unsigned short Bs1[16384];   // 32 KB stage B

  const int mat = blockIdx.y;
  const float* __restrict__ x = mat ? vp : kp;
  const unsigned short* __restrict__ wmat = wt + (size_t)mat * (BS * HD * HD);
  float* __restrict__ outp = out + (size_t)mat * out_half;

  const int tid = threadIdx.x, wid = tid >> 6, lane = tid & 63;
  const int fl = lane & 15, fq = lane >> 4;
  const int mbase = blockIdx.x * 64 + wid * 16;

  // Per-lane token base for this wave's 16-row m-fragment.
  int m = mbase + fl;
  int mc = m < M_total ? m : M_total - 1;
  int o = mc >> 2, h = mc & 3;
  int tb = 0, accb = 0;
  for (int b = 0; b < num_seqs; ++b) {
    int c0 = cu[b], c1 = cu[b + 1];
    int ol = (c1 - c0 - BS) / STRIDE;
    if (o >= accb && o - accb < ol) tb = c0 + (o - accb) * STRIDE;
    accb += ol;
  }
  const float* __restrict__ arow = x + ((size_t)tb * NH + h) * HD + fq * 8;

  floatx4 acc[8];
#pragma unroll
  for (int ni = 0; ni < 8; ++ni) acc[ni] = (floatx4){0.f, 0.f, 0.f, 0.f};

  float4 a[2][4][2];   // [parity][k0][half]

  // Stage full j-slice (32 KB) into buffer BW: 8 gld16/lane, linear dest.
#define BSTAGE(J, BW)                                                       \
  {                                                                         \
    const unsigned short* s_ = wmat + (size_t)(J) * 16384 + tid * 8;        \
    _Pragma("unroll") for (int i_ = 0; i_ < 8; ++i_)                        \
        gld16(s_ + i_ * 2048, &BW[i_ * 2048 + tid * 8]);                    \
  }

  // Prefetch A for column j into parity P: 8 dwordx4/lane.
#define ALOAD(JN, P)                                                        \
  {                                                                         \
    const float* ar_ = arow + (size_t)(JN) * (NH * HD);                     \
    _Pragma("unroll") for (int k_ = 0; k_ < 4; ++k_) {                      \
      a[(P)][k_][0] = *(const float4*)(ar_ + k_ * 32);                      \
      a[(P)][k_][1] = *(const float4*)(ar_ + k_ * 32 + 4);                  \
    }                                                                       \
  }

  // 32 MFMA: 8 n-frags x 4 k0 from buffer BR.
#define COMPUTE(P, BR)                                                      \
  {                                                                         \
    bf16x8 af_[4];                                                          \
    _Pragma("unroll") for (int k_ = 0; k_ < 4; ++k_)                        \
        af_[k_] = cvt8(a[(P)][k_][0], a[(P)][k_][1]);                       \
    _Pragma("unroll") for (int k_ = 0; k_ < 4; ++k_) {                      \
      _Pragma("unroll") for (int ni_ = 0; ni_ < 8; ++ni_) {                 \
        bf16x8 bf_ = *(const bf16x8*)&BR[k_ * 4096 + fq * 1024 +            \
                                         (ni_ * 16 + fl) * 8];              \
        acc[ni_] = __builtin_amdgcn_mfma_f32_16x16x32_bf16(                 \
            af_[k_], bf_, acc[ni_], 0, 0, 0);                               \
      }                                                                     \
    }                                                                       \
  }

#define VWAIT_(N) asm volatile("s_waitcnt vmcnt(" #N ")" ::: "memory")
#define VWAIT(N) VWAIT_(N)

  // One K-step. Barrier #1: all waves done reading BW (prev use). Issue next
  // stage+prefetch into BW/parity, counted wait (prev step's 16 ops landed,
  // this step's 16 stay in flight), barrier #2: BR staged & visible.
#define STEP(J, BR, BW, PA, JN, NV, PRE)                                    \
  {                                                                         \
    __builtin_amdgcn_s_barrier();                                           \
    __builtin_amdgcn_sched_barrier(0);                                      \
    if (PRE) {                                                              \
      BSTAGE((JN), BW);                                                     \
      ALOAD((JN), (PA) ^ 1);                                                \
    }                                                                       \
    __builtin_amdgcn_sched_barrier(0);                                      \
    VWAIT(NV);                                                              \
    __builtin_amdgcn_sched_barrier(0);                                      \
    __builtin_amdgcn_s_barrier();                                           \
    __builtin_amdgcn_sched_barrier(0);                                      \
    COMPUTE((PA), BR);                                                      \
  }

  BSTAGE(0, Bs0);
  ALOAD(0, 0);
  for (int j = 0; j < 30; j += 2) {
    STEP(j, Bs0, Bs1, 0, j + 1, 16, 1);
    STEP(j + 1, Bs1, Bs0, 1, j + 2, 16, 1);
  }
  STEP(30, Bs0, Bs1, 0, 31, 16, 1);
  STEP(31, Bs1, Bs0, 1, 0, 0, 0);

#undef STEP
#undef VWAIT
#undef VWAIT_
#undef COMPUTE
#undef ALOAD
#undef BSTAGE

  // C/D: col = fl (= e offset), row = fq*4 + r.
#pragma unroll
  for (int ni = 0; ni < 8; ++ni) {
#pragma unroll
    for (int r = 0; r < 4; ++r) {
      const int mg = mbase + fq * 4 + r;
      if (mg < M_total) outp[(size_t)mg * HD + ni * 16 + fl] = acc[ni][r];
    }
  }
}

// Fallback path if ws is too small for the weight transpose.
__global__ void tail_kernel(const int* __restrict__ cu, int num_seqs,
                            float* __restrict__ tail) {
  if (threadIdx.x == 0) {
    int acc = 0;
    tail[0] = 0.0f;
    for (int b = 0; b < num_seqs; ++b) {
      int n = cu[b + 1] - cu[b];
      acc += (n - BS) / STRIDE;
      tail[b + 1] = (float)acc;
    }
  }
}

__global__ void kvc_naive(const float* __restrict__ kp, const float* __restrict__ vp,
                          const float* __restrict__ wk, const float* __restrict__ wv,
                          const int* __restrict__ cu, int num_seqs,
                          float* __restrict__ out, long out_half) {
  int o = blockIdx.x, h = blockIdx.y, mat = blockIdx.z;
  int e = threadIdx.x;
  int acc = 0, base = -1;
  for (int b = 0; b < num_seqs; ++b) {
    int n = cu[b + 1] - cu[b];
    int ol = (n - BS) / STRIDE;
    if (o < acc + ol) { base = cu[b] + (o - acc) * STRIDE; break; }
    acc += ol;
  }
  if (base < 0) return;
  const float* x = mat ? vp : kp;
  const float* w = mat ? wv : wk;
  float s = 0.f;
  for (int j = 0; j < BS; ++j)
    for (int d = 0; d < HD; ++d)
      s += x[(size_t)(base + j) * (NH * HD) + h * HD + d] * w[(j * HD + d) * HD + e];
  out[(size_t)mat * out_half + ((size_t)o * NH + h) * HD + e] = s;
}

extern "C" void kernel_launch(void* const* d_in, const int* in_sizes, int n_in,
                              void* d_out, int out_size, void* d_ws, size_t ws_size,
                              hipStream_t stream) {
  const float* kp = (const float*)d_in[0];
  const float* vp = (const float*)d_in[1];
  const float* wk = (const float*)d_in[2];
  const float* wv = (const float*)d_in[3];
  const int* cu = (const int*)d_in[4];
  const int num_seqs = in_sizes[4] - 1;
  float* out = (float*)d_out;

  const long total_out = ((long)out_size - (num_seqs + 1)) / (2L * NH * HD);
  const long out_half = total_out * NH * HD;
  const int M_total = (int)(total_out * NH);
  float* tail = out + 2 * out_half;

  const size_t need_ws = (size_t)2 * BS * HD * HD * sizeof(unsigned short);
  if (ws_size >= need_ws) {
    unsigned short* wt = (unsigned short*)d_ws;
    prep_kernel<<<2 * BS * 4 + 1, 256, 0, stream>>>(wk, wv, wt, cu, num_seqs, tail);
    dim3 grid((M_total + 63) / 64, 2);
    kvc_gemm<<<grid, 256, 0, stream>>>(kp, vp, wt, cu, out, out_half, M_total,
                                       num_seqs);
  } else {
    tail_kernel<<<1, 64, 0, stream>>>(cu, num_seqs, tail);
    dim3 grid((unsigned)total_out, NH, 2);
    kvc_naive<<<grid, HD, 0, stream>>>(kp, vp, wk, wv, cu, num_seqs, out, out_half);
  }
}